// Round 3
// baseline (329.816 us; speedup 1.0000x reference)
//
#include <hip/hip_runtime.h>

typedef __attribute__((ext_vector_type(8))) short short8;
typedef __attribute__((ext_vector_type(4))) float floatx4;

#define NEG_SLOPE 0.01f

__device__ __forceinline__ unsigned bfr(float f) {
    // round-to-nearest-even fp32 -> bf16 (in low 16 bits)
    unsigned u = __float_as_uint(f);
    return (u + 0x7FFFu + ((u >> 16) & 1u)) >> 16;
}
__device__ __forceinline__ int pack2(float x, float y) {
    return (int)bfr(x) | (int)(bfr(y) << 16);
}
__device__ __forceinline__ short8 packfrag(float4 a, float4 b) {
    union { int i[4]; short8 s; } u;
    u.i[0] = pack2(a.x, a.y); u.i[1] = pack2(a.z, a.w);
    u.i[2] = pack2(b.x, b.y); u.i[3] = pack2(b.z, b.w);
    return u.s;
}

// One block = (b, 4 consecutive i); one wave per i. ZERO barriers, no shared
// staging: E_b (16 KB) and W (16 KB) are L1/L2-resident, read directly.
// Wave timeline: (1) 16 coalesced nontemporal value-stores fire immediately;
// (2) qk = E_b @ (W * e_i)^T via mfma_f32_16x16x32_bf16, fragments converted
// in-register; (3) leaky+dot+softmax via shuffles; wave-local LDS transpose
// (no s_barrier -> no vmcnt(0) store drain anywhere).
__global__ __launch_bounds__(256, 4)
void afm_kernel(const float* __restrict__ emb,
                const float* __restrict__ wW,
                const float* __restrict__ wb,
                const float* __restrict__ aW,
                float* __restrict__ aOut,
                float* __restrict__ vOut) {
    __shared__ float slog[4][64];   // wave-private rows only

    const int tid  = threadIdx.x;
    const int lane = tid & 63;
    const int w    = tid >> 6;           // wave id 0..3
    const int lo   = lane & 15;
    const int hi   = lane >> 4;
    const int blk  = blockIdx.x;
    const int b    = blk >> 4;           // 0..255
    const int i    = ((blk & 15) << 2) + w;

    const float* embB   = emb + ((size_t)b << 12);
    const float* ei_row = embB + (i << 6);

    // ---------------- value stream: fire-and-forget, no dependencies --------
    {
        float4 ei = *(const float4*)(ei_row + (lo << 2));
        float* base = vOut + (((size_t)((b << 6) + i)) << 12) + (lane << 2);
        #pragma unroll
        for (int c = 0; c < 16; ++c) {
            // lanes 0..63 cover rows 4c..4c+3 cols 0..63 -> one 1KB coalesced read (L1)
            float4 ej = *(const float4*)(embB + ((((c << 2) + hi)) << 6) + (lo << 2));
            floatx4 v;
            v[0] = ei.x * ej.x; v[1] = ei.y * ej.y;
            v[2] = ei.z * ej.z; v[3] = ei.w * ej.w;
            __builtin_nontemporal_store(v, (floatx4*)(base + (c << 8)));
        }
    }

    // ---------------- qk[j,e] = sum_d E[j][d] * (W[e][d]*ei[d]) via MFMA ----
    // A-frag: lane holds E[jt*16+lo][kt*32+hi*8 .. +7]
    // B-frag: lane holds W[et*16+lo][k]*ei[k], k = kt*32+hi*8 .. +7
    // C/D:    col(e-res)=lo, row(j-res)=hi*4+r
    floatx4 acc[4][4];
    #pragma unroll
    for (int jt = 0; jt < 4; ++jt)
        #pragma unroll
        for (int et = 0; et < 4; ++et)
            acc[jt][et] = (floatx4){0.f, 0.f, 0.f, 0.f};

    #pragma unroll
    for (int kt = 0; kt < 2; ++kt) {
        const int d0 = (kt << 5) + (hi << 3);
        float4 ei0 = *(const float4*)(ei_row + d0);        // 16-lane broadcast (L1)
        float4 ei1 = *(const float4*)(ei_row + d0 + 4);
        short8 bfrag[4];
        #pragma unroll
        for (int et = 0; et < 4; ++et) {
            const float* pw = wW + ((((et << 4) + lo)) << 6) + d0;
            float4 w0 = *(const float4*)(pw);
            float4 w1 = *(const float4*)(pw + 4);
            float4 p0, p1;
            p0.x = w0.x * ei0.x; p0.y = w0.y * ei0.y;
            p0.z = w0.z * ei0.z; p0.w = w0.w * ei0.w;
            p1.x = w1.x * ei1.x; p1.y = w1.y * ei1.y;
            p1.z = w1.z * ei1.z; p1.w = w1.w * ei1.w;
            bfrag[et] = packfrag(p0, p1);
        }
        #pragma unroll
        for (int jt = 0; jt < 4; ++jt) {
            const float* pe = embB + ((((jt << 4) + lo)) << 6) + d0;
            float4 a0 = *(const float4*)(pe);
            float4 a1 = *(const float4*)(pe + 4);
            short8 afrag = packfrag(a0, a1);
            #pragma unroll
            for (int et = 0; et < 4; ++et)
                acc[jt][et] = __builtin_amdgcn_mfma_f32_16x16x32_bf16(
                    afrag, bfrag[et], acc[jt][et], 0, 0, 0);
        }
    }

    // ---------------- epilogue: bias + leaky + aW dot + 64-wide softmax -----
    float wbv[4], awv[4];
    #pragma unroll
    for (int et = 0; et < 4; ++et) {
        wbv[et] = wb[(et << 4) + lo];    // tiny, L1 broadcast
        awv[et] = aW[(et << 4) + lo];
    }

    float lg[16];
    #pragma unroll
    for (int jt = 0; jt < 4; ++jt) {
        #pragma unroll
        for (int r = 0; r < 4; ++r) {
            float p = 0.f;
            #pragma unroll
            for (int et = 0; et < 4; ++et) {
                float x = acc[jt][et][r] + wbv[et];
                x = (x >= 0.f) ? x : NEG_SLOPE * x;
                p += awv[et] * x;
            }
            p += __shfl_xor(p, 1);
            p += __shfl_xor(p, 2);
            p += __shfl_xor(p, 4);
            p += __shfl_xor(p, 8);
            lg[jt * 4 + r] = p;          // logit[j], j = jt*16 + hi*4 + r
        }
    }

    float m = lg[0];
    #pragma unroll
    for (int k = 1; k < 16; ++k) m = fmaxf(m, lg[k]);
    m = fmaxf(m, __shfl_xor(m, 16));
    m = fmaxf(m, __shfl_xor(m, 32));

    float ex[16];
    float s = 0.f;
    #pragma unroll
    for (int k = 0; k < 16; ++k) { ex[k] = __expf(lg[k] - m); s += ex[k]; }
    s += __shfl_xor(s, 16);
    s += __shfl_xor(s, 32);
    float inv = 1.f / s;

    // wave-local transpose through LDS (no cross-wave dep -> no s_barrier)
    if (lo == 0) {
        #pragma unroll
        for (int jt = 0; jt < 4; ++jt)
            #pragma unroll
            for (int r = 0; r < 4; ++r)
                slog[w][jt * 16 + hi * 4 + r] = ex[jt * 4 + r] * inv;
    }
    asm volatile("" ::: "memory");       // order ds_read after ds_write
    aOut[(((size_t)((b << 6) + i)) << 6) + lane] = slog[w][lane];
}

extern "C" void kernel_launch(void* const* d_in, const int* in_sizes, int n_in,
                              void* d_out, int out_size, void* d_ws, size_t ws_size,
                              hipStream_t stream) {
    const float* emb = (const float*)d_in[0];   // [256,64,64]
    const float* wW  = (const float*)d_in[1];   // [64,64]
    const float* wb  = (const float*)d_in[2];   // [64]
    const float* aW  = (const float*)d_in[3];   // [64]
    // d_in[4] = a_b : softmax is shift-invariant, unused.
    float* aOut = (float*)d_out;                 // [256,64,64,1]
    float* vOut = aOut + (size_t)256 * 64 * 64;  // [256,64,64,64]
    afm_kernel<<<4096, 256, 0, stream>>>(emb, wW, wb, aW, aOut, vOut);
}

// Round 4
// 305.274 us; speedup vs baseline: 1.0804x; 1.0804x over previous
//
#include <hip/hip_runtime.h>

typedef __attribute__((ext_vector_type(8))) short short8;
typedef __attribute__((ext_vector_type(4))) float floatx4;
typedef __attribute__((ext_vector_type(4))) int   intx4;

#define NEG_SLOPE 0.01f

__device__ __forceinline__ unsigned bfr(float f) {
    // round-to-nearest-even fp32 -> bf16 (in low 16 bits)
    unsigned u = __float_as_uint(f);
    return (u + 0x7FFFu + ((u >> 16) & 1u)) >> 16;
}
__device__ __forceinline__ int pack2(float x, float y) {
    return (int)bfr(x) | (int)(bfr(y) << 16);
}
__device__ __forceinline__ short8 packfrag(float4 a, float4 b) {
    union { int i[4]; short8 s; } u;
    u.i[0] = pack2(a.x, a.y); u.i[1] = pack2(a.z, a.w);
    u.i[2] = pack2(b.x, b.y); u.i[3] = pack2(b.z, b.w);
    return u.s;
}

// One block = (b, 4 consecutive i); one wave per i.
// Key structure: ALL global loads (stage-E, ei, W, wb, aW) issue before any
// value-store, so the vmcnt FIFO never makes compute wait behind store drain.
// E_b staged in LDS (fp32 for value phase, bf16 for MFMA A-frags); W read from
// global (identical for all blocks -> L1-hot). After the single __syncthreads,
// only LDS (lgkmcnt) is touched by the MFMA path. No barrier after stores.
__global__ __launch_bounds__(256, 4)
void afm_kernel(const float* __restrict__ emb,
                const float* __restrict__ wW,
                const float* __restrict__ wb,
                const float* __restrict__ aW,
                float* __restrict__ aOut,
                float* __restrict__ vOut) {
    __shared__ __align__(16) float sEf[64][68];   // E_b fp32, stride 68 (minimal-conflict)
    __shared__ __align__(16) short sEb[64][72];   // E_b bf16, stride 72 shorts (144 B)
    __shared__ float slog[4][64];                 // wave-private softmax transpose

    const int tid  = threadIdx.x;
    const int lane = tid & 63;
    const int w    = tid >> 6;           // wave id 0..3
    const int lo   = lane & 15;
    const int hi   = lane >> 4;
    const int blk  = blockIdx.x;
    const int b    = blk >> 4;           // 0..255
    const int i    = ((blk & 15) << 2) + w;

    const float* embB   = emb + ((size_t)b << 12);
    const float* ei_row = embB + (i << 6);

    // ---- 1) stage loads: E_b rows (coalesced 16 floats/thread) -------------
    const int srow = tid >> 2;
    const int c0   = (tid & 3) << 4;
    const float* src = embB + (srow << 6) + c0;
    float4 a0 = *(const float4*)(src);
    float4 a1 = *(const float4*)(src + 4);
    float4 a2 = *(const float4*)(src + 8);
    float4 a3 = *(const float4*)(src + 12);

    // ---- 2) ei fragments (L1/L2-hit broadcasts) ----------------------------
    float4 eiv = *(const float4*)(ei_row + (lo << 2));       // for value phase
    float4 ei0[2], ei1[2];
    #pragma unroll
    for (int kt = 0; kt < 2; ++kt) {
        const int d0 = (kt << 5) + (hi << 3);
        ei0[kt] = *(const float4*)(ei_row + d0);
        ei1[kt] = *(const float4*)(ei_row + d0 + 4);
    }

    // ---- 3) W loads + B-fragments: bf16(W[e,d] * ei[d]) --------------------
    short8 bfragAll[2][4];
    #pragma unroll
    for (int kt = 0; kt < 2; ++kt) {
        const int d0 = (kt << 5) + (hi << 3);
        #pragma unroll
        for (int et = 0; et < 4; ++et) {
            const float* pw = wW + (((et << 4) + lo) << 6) + d0;
            float4 w0 = *(const float4*)(pw);
            float4 w1 = *(const float4*)(pw + 4);
            float4 p0, p1;
            p0.x = w0.x * ei0[kt].x; p0.y = w0.y * ei0[kt].y;
            p0.z = w0.z * ei0[kt].z; p0.w = w0.w * ei0[kt].w;
            p1.x = w1.x * ei1[kt].x; p1.y = w1.y * ei1[kt].y;
            p1.z = w1.z * ei1[kt].z; p1.w = w1.w * ei1[kt].w;
            bfragAll[kt][et] = packfrag(p0, p1);
        }
    }

    // ---- 4) epilogue constants (issued early, consumed late) ---------------
    float wbv[4], awv[4];
    #pragma unroll
    for (int et = 0; et < 4; ++et) {
        wbv[et] = wb[(et << 4) + lo];
        awv[et] = aW[(et << 4) + lo];
    }

    // ---- 5) LDS stage write (fp32 + bf16) + the ONLY block barrier ---------
    *(float4*)&sEf[srow][c0]      = a0;
    *(float4*)&sEf[srow][c0 + 4]  = a1;
    *(float4*)&sEf[srow][c0 + 8]  = a2;
    *(float4*)&sEf[srow][c0 + 12] = a3;
    intx4 q0, q1;
    q0[0] = pack2(a0.x, a0.y); q0[1] = pack2(a0.z, a0.w);
    q0[2] = pack2(a1.x, a1.y); q0[3] = pack2(a1.z, a1.w);
    q1[0] = pack2(a2.x, a2.y); q1[1] = pack2(a2.z, a2.w);
    q1[2] = pack2(a3.x, a3.y); q1[3] = pack2(a3.z, a3.w);
    *(intx4*)&sEb[srow][c0]     = q0;
    *(intx4*)&sEb[srow][c0 + 8] = q1;
    __syncthreads();

    // ---- 6) value stream: LDS read -> fire-and-forget coalesced stores -----
    {
        float* base = vOut + (((size_t)((b << 6) + i)) << 12) + (lane << 2);
        #pragma unroll
        for (int c = 0; c < 16; ++c) {
            float4 ej = *(float4*)&sEf[(c << 2) + hi][lo << 2];
            float4 v;
            v.x = eiv.x * ej.x; v.y = eiv.y * ej.y;
            v.z = eiv.z * ej.z; v.w = eiv.w * ej.w;
            *(float4*)(base + (c << 8)) = v;   // 1 KB coalesced per instr
        }
    }

    // ---- 7) qk[j,e] = sum_d E[j][d]*(W[e][d]*ei[d]) via MFMA (LDS-only) ----
    floatx4 acc[4][4];
    #pragma unroll
    for (int jt = 0; jt < 4; ++jt)
        #pragma unroll
        for (int et = 0; et < 4; ++et)
            acc[jt][et] = (floatx4){0.f, 0.f, 0.f, 0.f};

    #pragma unroll
    for (int kt = 0; kt < 2; ++kt) {
        const int d0 = (kt << 5) + (hi << 3);
        #pragma unroll
        for (int jt = 0; jt < 4; ++jt) {
            short8 afrag = *(short8*)&sEb[(jt << 4) + lo][d0];
            #pragma unroll
            for (int et = 0; et < 4; ++et)
                acc[jt][et] = __builtin_amdgcn_mfma_f32_16x16x32_bf16(
                    afrag, bfragAll[kt][et], acc[jt][et], 0, 0, 0);
        }
    }

    // ---- 8) epilogue: bias + leaky + aW dot + 64-wide softmax --------------
    float lg[16];
    #pragma unroll
    for (int jt = 0; jt < 4; ++jt) {
        #pragma unroll
        for (int r = 0; r < 4; ++r) {
            float p = 0.f;
            #pragma unroll
            for (int et = 0; et < 4; ++et) {
                float x = acc[jt][et][r] + wbv[et];
                x = (x >= 0.f) ? x : NEG_SLOPE * x;
                p += awv[et] * x;
            }
            p += __shfl_xor(p, 1);
            p += __shfl_xor(p, 2);
            p += __shfl_xor(p, 4);
            p += __shfl_xor(p, 8);
            lg[jt * 4 + r] = p;          // logit[j], j = jt*16 + hi*4 + r
        }
    }

    float m = lg[0];
    #pragma unroll
    for (int k = 1; k < 16; ++k) m = fmaxf(m, lg[k]);
    m = fmaxf(m, __shfl_xor(m, 16));
    m = fmaxf(m, __shfl_xor(m, 32));

    float ex[16];
    float s = 0.f;
    #pragma unroll
    for (int k = 0; k < 16; ++k) { ex[k] = __expf(lg[k] - m); s += ex[k]; }
    s += __shfl_xor(s, 16);
    s += __shfl_xor(s, 32);
    float inv = 1.f / s;

    // wave-local transpose through LDS (no cross-wave dep -> no s_barrier)
    if (lo == 0) {
        #pragma unroll
        for (int jt = 0; jt < 4; ++jt)
            #pragma unroll
            for (int r = 0; r < 4; ++r)
                slog[w][jt * 16 + hi * 4 + r] = ex[jt * 4 + r] * inv;
    }
    asm volatile("" ::: "memory");       // order ds_read after ds_write
    aOut[(((size_t)((b << 6) + i)) << 6) + lane] = slog[w][lane];
}

extern "C" void kernel_launch(void* const* d_in, const int* in_sizes, int n_in,
                              void* d_out, int out_size, void* d_ws, size_t ws_size,
                              hipStream_t stream) {
    const float* emb = (const float*)d_in[0];   // [256,64,64]
    const float* wW  = (const float*)d_in[1];   // [64,64]
    const float* wb  = (const float*)d_in[2];   // [64]
    const float* aW  = (const float*)d_in[3];   // [64]
    // d_in[4] = a_b : softmax is shift-invariant, unused.
    float* aOut = (float*)d_out;                 // [256,64,64,1]
    float* vOut = aOut + (size_t)256 * 64 * 64;  // [256,64,64,64]
    afm_kernel<<<4096, 256, 0, stream>>>(emb, wW, wb, aW, aOut, vOut);
}